// Round 9
// baseline (132.123 us; speedup 1.0000x reference)
//
#include <hip/hip_runtime.h>
#include <math.h>

#define NCLS 21
#define NCO 20
#define SUB 12                 // blocks per class in maskp/resolveout (R25-proven)
#define TPB 256                // resolveout block size
#define RCAP 2048
#define RMAX 2000
#define LDSW 7680              // u64 capacity of resolve LDS stage (60 KB)
#define SCORE_THRESH 0.05f

typedef unsigned long long u64;
typedef unsigned int u32;
typedef unsigned short u16;

// Exact equivalent of (f32_div(inter,uni) > 0.3f):  inter > IOU_MID * uni in f64.
// 0.3f = 10066330*2^-25; midpoint to next float = 20132661*2^-26. RN tie at the
// midpoint rounds to even (0.3f) -> false, matching strict ">". 25b x 24b exact in f64.
#define IOU_MID (20132661.0 / 67108864.0)

__device__ __forceinline__ u64 readlane64(u64 v, int l) {
    u32 lo = (u32)__builtin_amdgcn_readlane((int)(u32)v, l);
    u32 hi = (u32)__builtin_amdgcn_readlane((int)(u32)(v >> 32), l);
    return ((u64)hi << 32) | lo;
}
__device__ __forceinline__ float readlanef(float v, int l) {
    return __uint_as_float((u32)__builtin_amdgcn_readlane((int)__float_as_uint(v), l));
}
__device__ __forceinline__ u64 shflxor64(u64 v, int m) {
    u32 lo = (u32)__shfl_xor((int)(u32)v, m, 64);
    u32 hi = (u32)__shfl_xor((int)(u32)(v >> 32), m, 64);
    return ((u64)hi << 32) | lo;
}

// Compact upper-triangle mask layout, per class:
// chunk ic (64 rows) starts at coff(ic); row (ic<<6)+il has W=nw-ic words
// (words v=ic..nw-1) at coff(ic) + il*W + (v-ic). Total = coff(nw) words.
__device__ __forceinline__ int coff(int ic, int nw) {
    return ((ic * nw - ((ic * (ic - 1)) >> 1)) << 6);
}

// Reference-exact box decode (absmax 0.0 through R1-R25).
__device__ __forceinline__ void decode_box(
    const float* __restrict__ rois, const float* __restrict__ loc,
    int r, int cls, float sh, float sw,
    float& by1, float& bx1, float& by2, float& bx2)
{
    float4 rb = *(const float4*)(rois + r * 4);
    float y1 = rb.x, x1 = rb.y, y2 = rb.z, x2 = rb.w;
    float h = y2 - y1, w = x2 - x1;
    float cy = y1 + 0.5f * h, cx = x1 + 0.5f * w;
    float4 l4 = *(const float4*)(loc + r * (NCLS * 4) + cls * 4);
    float dy = l4.x * 0.1f, dx = l4.y * 0.1f;
    float dh = l4.z * 0.2f, dw = l4.w * 0.2f;
    float ncy = dy * h + cy, ncx = dx * w + cx;
    float nh = expf(dh) * h, nw = expf(dw) * w;
    by1 = fminf(fmaxf(ncy - 0.5f * nh, 0.f), sh);
    bx1 = fminf(fmaxf(ncx - 0.5f * nw, 0.f), sw);
    by2 = fminf(fmaxf(ncy + 0.5f * nh, 0.f), sh);
    bx2 = fminf(fmaxf(ncx + 0.5f * nw, 0.f), sw);
}

// Reference-exact softmax prob (vectorized loads; float op ORDER k=0..20 kept
// identical to prior rounds: max then exp-sum in index order).
__device__ __forceinline__ float softmax_p(
    const float* __restrict__ scores, int r, int cls)
{
    const float* srow = scores + r * NCLS;
    float s[NCLS];
    float4 a0 = *(const float4*)(srow);
    float4 a1 = *(const float4*)(srow + 4);
    float4 a2 = *(const float4*)(srow + 8);
    float4 a3 = *(const float4*)(srow + 12);
    float4 a4 = *(const float4*)(srow + 16);
    s[0]=a0.x; s[1]=a0.y; s[2]=a0.z; s[3]=a0.w;
    s[4]=a1.x; s[5]=a1.y; s[6]=a1.z; s[7]=a1.w;
    s[8]=a2.x; s[9]=a2.y; s[10]=a2.z; s[11]=a2.w;
    s[12]=a3.x; s[13]=a3.y; s[14]=a3.z; s[15]=a3.w;
    s[16]=a4.x; s[17]=a4.y; s[18]=a4.z; s[19]=a4.w;
    s[20]=srow[20];
    float m = -INFINITY;
#pragma unroll
    for (int k = 0; k < NCLS; ++k) m = fmaxf(m, s[k]);
    float sum = 0.f, ec = 0.f;
#pragma unroll
    for (int k = 0; k < NCLS; ++k) {
        float e = expf(s[k] - m);
        sum += e;
        if (k == cls) ec = e;
    }
    return ec / sum;
}

// ---------------------------------------------------------------------------
// R26: 3-dispatch chain. R8-round post-mortem: with fills fixed at ~81us and
// phase work ~12-16us, the 4 dispatch launch/boundary costs (~3-4us each) are
// the largest addressable slice. sortrank fuses keygen+rank LOSSLESSLY via
// one-block-per-class (20 x 1024): all 2000 softmax evals for the class in
// one block (same total work as the 240-block keygen, R19-proven ballot
// compact), then the R22-proven 4-way-split rank PARTITIONED over the
// block's 256 4-lane groups (each key ranked once - no R7-style redundancy),
// decode-once to pbG/arG + ord/nvv. Removes one boundary + the ukey/cntA
// global round-trip. maskp/resolveout are R25-proven verbatim (SUB=12).
// ---------------------------------------------------------------------------
__global__ __launch_bounds__(1024) void sortrank_kernel(
    const float* __restrict__ loc, const float* __restrict__ scores,
    const float* __restrict__ rois, const int* __restrict__ ph,
    const int* __restrict__ pw, u64* __restrict__ ord,
    int* __restrict__ nvv, float4* __restrict__ pbG,
    float* __restrict__ arG, int R)
{
    __shared__ __align__(16) u64 vkey[RCAP + 2];
    __shared__ int cnt;
    const int t = threadIdx.x;
    const int c = blockIdx.x;          // class-1 index 0..19
    const int lane = t & 63;
    if (t == 0) cnt = 0;
    __syncthreads();

    // ---- softmax + ballot compaction (one LDS atomic per wave-iteration) --
    // Within a wave, loop-active lanes form a lane-prefix (r grows with
    // lane), so lane 0 is always active when any lane is.
    for (int r = t; r < R; r += 1024) {
        float p = softmax_p(scores, r, c + 1);
        bool valid = (p > SCORE_THRESH);
        u64 key = ((u64)(~__float_as_uint(p)) << 32) | (u32)r;
        u64 bal = __ballot(valid);
        if (bal) {
            int nb = (int)__popcll(bal);
            int base = 0;
            if (lane == 0) base = atomicAdd(&cnt, nb);
            base = __shfl(base, 0, 64);
            if (valid)
                vkey[base + (int)__popcll(bal & ((1ull << lane) - 1ull))] = key;
        }
    }
    __syncthreads();
    const int nv = cnt;
    if (t == 0) { vkey[nv] = ~0ull; nvv[c] = nv; }  // sentinel for b128 pairs
    __syncthreads();

    // ---- 4-way-split rank, partitioned over 256 4-lane groups -------------
    const int q = t & 3;               // j-quarter; 4-lane group = one key
    const ulonglong2* vk2 = (const ulonglong2*)vkey;
    const int nj2 = (nv + 1) >> 1;
    const int jb0 = (q * nj2) >> 2;
    const int jb1 = ((q + 1) * nj2) >> 2;
    const float shf = (float)(*ph), swf = (float)(*pw);
    for (int il = (t >> 2); il < nv; il += 256) {
        u64 kk = vkey[il];
        int rank = 0;
#pragma unroll 8
        for (int j = jb0; j < jb1; ++j) {
            ulonglong2 kj = vk2[j];    // same-address broadcast, 16B
            rank += (int)(kj.x < kk) + (int)(kj.y < kk);
        }
        rank += __shfl_xor(rank, 1, 64);   // combine 4-lane group
        rank += __shfl_xor(rank, 2, 64);   // (integer, exact)
        if (q == 0) {
            int r = (int)(u32)kk;
            float b0, b1, b2, b3;
            decode_box(rois, loc, r, c + 1, shf, swf, b0, b1, b2, b3);
            ord[((size_t)c << 11) + rank] = kk;
            pbG[((size_t)c << 11) + rank] = make_float4(b0, b1, b2, b3);
            arG[((size_t)c << 11) + rank] = (b2 - b0) * (b3 - b1);
        }
    }
}

// ---------------------------------------------------------------------------
// maskp: 240 blocks x 512 (R25-proven verbatim). Loads pre-decoded sorted
// boxes (coalesced float4, no exp) into LDS; proven wide mask structure,
// 96 waves/class (~1.4 upper-tri tasks each).
// ---------------------------------------------------------------------------
__global__ __launch_bounds__(512) void maskp_kernel(
    const float4* __restrict__ pbG, const float* __restrict__ arG,
    const int* __restrict__ nvv, u64* __restrict__ M)
{
    __shared__ float4 pb[RCAP];        // 32 KB sorted boxes
    __shared__ float ar[RCAP];         // 8 KB areas
    const int t = threadIdx.x;
    const int c = blockIdx.x / SUB;
    const int s = blockIdx.x % SUB;
    const int lane = t & 63;
    const int nv = nvv[c];
    const int nw = (nv + 63) >> 6;
    for (int i = t; i < nv; i += 512) {
        pb[i] = pbG[((size_t)c << 11) + i];
        ar[i] = arG[((size_t)c << 11) + i];
    }
    __syncthreads();

    const int wid = (s << 3) | (t >> 6);     // 0..SUB*8-1 waves per class
    const int ntasks = nw * (nw + 1) / 2;
    u64* Mc = M + ((size_t)c << 16);
    for (int task = wid; task < ntasks; task += SUB * 8) {
        int ic = 0, rm = task;
        while (rm >= nw - ic) { rm -= nw - ic; ++ic; }  // uniform, <=32 iters
        int v = ic + rm;
        int i = (ic << 6) + lane;
        float4 a = pb[i];                    // garbage if i>=nv (not stored)
        float iarea = ar[i];
        float4 rj = pb[(v << 6) + lane];     // loads executed by all lanes
        float ja_l = ar[(v << 6) + lane];
        int jcnt = min(64, nv - (v << 6));
        u64 m = 0;
        for (int jj = 0; jj < jcnt; ++jj) {
            float jy1 = readlanef(rj.x, jj);
            float jx1 = readlanef(rj.y, jj);
            float jy2 = readlanef(rj.z, jj);
            float jx2 = readlanef(rj.w, jj);
            float ja  = readlanef(ja_l, jj);
            float ty1 = fmaxf(a.x, jy1);
            float tx1 = fmaxf(a.y, jx1);
            float ty2 = fminf(a.z, jy2);
            float tx2 = fminf(a.w, jx2);
            float inter = fmaxf(ty2 - ty1, 0.f) * fmaxf(tx2 - tx1, 0.f);
            float uni = fmaxf(iarea + ja - inter, 1e-10f);
            if ((double)inter > IOU_MID * (double)uni) m |= 1ull << jj;
        }
        if (v == ic) m &= (lane < 63) ? (~0ull << (lane + 1)) : 0ull;
        int W = nw - ic;
        if (i < nv) Mc[coff(ic, nw) + lane * W + (v - ic)] = m;
    }
}

// ---------------------------------------------------------------------------
// resolveout: 240 blocks x 256 (proven core, R25 verbatim). Each sub-block
// stages/reads the class's compact mask, runs the resolve, then zeroes +
// scatters its 1/12 output slice.
// ---------------------------------------------------------------------------
__global__ __launch_bounds__(TPB) void resolveout_kernel(
    const float* __restrict__ loc, const float* __restrict__ rois,
    const int* __restrict__ ph, const int* __restrict__ pw,
    const u64* __restrict__ ord, const int* __restrict__ nvv,
    const u64* __restrict__ M, float* __restrict__ out, int R)
{
    __shared__ u64 mlds[LDSW];         // 60 KB compact mask
    __shared__ u64 keptw[32];
    const int t = threadIdx.x;
    const int c = blockIdx.x / SUB;
    const int s = blockIdx.x % SUB;
    const int nv = nvv[c];
    const int nw = (nv + 63) >> 6;
    const u64* Mc = M + ((size_t)c << 16);
    const int S = coff(nw, nw);
    const bool lds_ok = (S <= LDSW);
    if (t < 32) keptw[t] = 0;

    if (lds_ok) {
        for (int base = 0; base < S; base += 2048) {
            u64 v[8];
#pragma unroll
            for (int j = 0; j < 8; ++j) {      // 8 independent coalesced loads
                int k = base + (j << 8) + t;
                v[j] = (k < S) ? Mc[k] : 0ull;
            }
#pragma unroll
            for (int j = 0; j < 8; ++j) {
                int k = base + (j << 8) + t;
                if (k < S) mlds[k] = v[j];
            }
        }
    }
    __syncthreads();

    if (t < 64) {
        const int lane = t;
        auto core = [&](const auto* B) {
            u64 remreg = 0;                 // lane l owns removed-word l
            for (int w = 0; w < nw; ++w) {
                const int W = nw - w;
                const int cb = coff(w, nw);
                int i = (w << 6) + lane;
                u64 cw = (i < nv) ? B[cb + lane * W] : 0ull;   // diagonal word
                int remn = nv - (w << 6);
                u64 vb = (remn >= 64) ? ~0ull : ((1ull << remn) - 1ull);
                u64 cand = vb & ~readlane64(remreg, w);
                u64 X = cand;
                if (X) {
                    // in-word greedy fixpoint (ballot Jacobi; strict upper
                    // triangle => contrib bit l only from rows j<l =>
                    // fixpoint = greedy by index induction). R15-proven.
                    for (int it = 0; it < 64; ++it) {
                        u64 contrib = ((X >> lane) & 1ull) ? cw : 0ull;
#pragma unroll
                        for (int d = 1; d < 64; d <<= 1)
                            contrib |= shflxor64(contrib, d);
                        bool keep = ((cand >> lane) & 1ull) &&
                                    !((contrib >> lane) & 1ull);
                        u64 Xn = __ballot(keep);
                        if (Xn == X) break;
                        X = Xn;
                    }
                    if (lane == 0) keptw[w] = X;
                    // 8-wide batched propagation into later rem words
                    // (lane v owns word v); km=X is wave-uniform.
                    bool lact = (lane > w) && (lane < nw);
                    u64 km = X, acc = 0;
                    while (km) {
                        int bs[8];
#pragma unroll
                        for (int g = 0; g < 8; ++g) {
                            bs[g] = km ? (__ffsll(km) - 1) : -1;
                            if (km) km &= km - 1;
                        }
                        u64 tmp[8];
#pragma unroll
                        for (int g = 0; g < 8; ++g)
                            tmp[g] = (bs[g] >= 0 && lact)
                                ? B[cb + bs[g] * W + (lane - w)] : 0ull;
#pragma unroll
                        for (int g = 0; g < 8; ++g) acc |= tmp[g];
                    }
                    if (lact) remreg |= acc;
                }
            }
        };
        if (lds_ok) core(mlds); else core(Mc);
    }
    __syncthreads();

    // Output: zero this sub-block's slice, barrier (drains stores), scatter
    // kept rows whose roi index falls in range (decode recompute + prob bits).
    const int chunk = (R + SUB - 1) / SUB;
    const int r0 = s * chunk;
    const int r1 = min(R, r0 + chunk);
    float* slice = out + (size_t)c * R * 5;
    for (int k = r0 * 5 + t; k < r1 * 5; k += TPB) slice[k] = 0.f;
    __syncthreads();                    // drains the zero stores (vmcnt(0))

    const float sh = (float)(*ph), sw = (float)(*pw);
    for (int i = t; i < nv; i += TPB) {
        if ((keptw[i >> 6] >> (i & 63)) & 1ull) {
            u64 key = ord[((size_t)c << 11) + i];
            int r = (int)(u32)key;
            if (r >= r0 && r < r1) {
                float v0, v1, v2, v3;
                decode_box(rois, loc, r, c + 1, sh, sw, v0, v1, v2, v3);
                float* p = slice + (size_t)r * 5;
                p[0] = v0; p[1] = v1; p[2] = v2; p[3] = v3;
                p[4] = __uint_as_float(~(u32)(key >> 32));
            }
        }
    }
}

// --------------------------- fallback: R4 fused ----------------------------
#define NTH 1024
__global__ __launch_bounds__(NTH) void fused_kernel(
    const float* __restrict__ loc, const float* __restrict__ scores,
    const float* __restrict__ rois, const int* __restrict__ ph,
    const int* __restrict__ pw, float* __restrict__ out, int R)
{
    __shared__ u64 vkey[RMAX];
    __shared__ float2 p1[RMAX], p2[RMAX];
    __shared__ u64 chunk[64 * 33];
    __shared__ u64 rem[32];
    __shared__ int cnt;

    const int t = threadIdx.x;
    const int lane = t & 63;
    const int c = blockIdx.x + 1;
    const float sh = (float)(*ph), sw = (float)(*pw);

    if (t == 0) cnt = 0;
    if (t < 32) rem[t] = 0;
    __syncthreads();

    for (int r = t; r < R; r += NTH) {
        float p = softmax_p(scores, r, c);
        if (p > SCORE_THRESH) {
            int j = atomicAdd(&cnt, 1);
            vkey[j] = ((u64)(~__float_as_uint(p)) << 32) | (u32)r;
        }
    }
    __syncthreads();
    const int nv = cnt;
    const int nw = (nv + 63) >> 6;

    u64 kk0 = 0, kk1 = 0;
    int r0 = 0, r1 = 0;
    bool in0 = (t < nv), in1 = (t + NTH < nv);
    if (in0) kk0 = vkey[t];
    if (in1) kk1 = vkey[t + NTH];
#pragma unroll 8
    for (int i = 0; i < nv; ++i) {
        u64 k = vkey[i];
        r0 += (k < kk0);
        r1 += (k < kk1);
    }
    __syncthreads();

    for (int u = 0; u < 2; ++u) {
        bool act = u ? in1 : in0;
        if (act) {
            u64 kk = u ? kk1 : kk0;
            int rank = u ? r1 : r0;
            int r = (int)(kk & 0xffffffffu);
            float b0, b1, b2, b3;
            decode_box(rois, loc, r, c, sh, sw, b0, b1, b2, b3);
            vkey[rank] = kk;
            p1[rank] = make_float2(b0, b1);
            p2[rank] = make_float2(b2, b3);
        }
    }
    __syncthreads();

    for (int w = 0; w < nw; ++w) {
        int nwr = nw - w;
        u64 remw = rem[w];
        for (int task = t; task < (nwr << 6); task += NTH) {
            int vr = task >> 6, il = task & 63;
            int i = (w << 6) + il;
            u64 m = 0;
            if (i < nv && !((remw >> il) & 1ull)) {
                int v = w + vr;
                u64 rv = rem[v];
                if (~rv != 0ull) {
                    float2 a1 = p1[i], a2 = p2[i];
                    float iarea = (a2.x - a1.x) * (a2.y - a1.y);
                    int j0 = v << 6;
                    int jhi = min(64, nv - j0);
#pragma unroll 4
                    for (int jj = 0; jj < jhi; ++jj) {
                        float2 b1 = p1[j0 + jj], b2 = p2[j0 + jj];
                        float ty1 = fmaxf(a1.x, b1.x);
                        float tx1 = fmaxf(a1.y, b1.y);
                        float ty2 = fminf(a2.x, b2.x);
                        float tx2 = fminf(a2.y, b2.y);
                        float inter = fmaxf(ty2 - ty1, 0.f) * fmaxf(tx2 - tx1, 0.f);
                        float jarea = (b2.x - b1.x) * (b2.y - b1.y);
                        float uni = fmaxf(iarea + jarea - inter, 1e-10f);
                        if ((double)inter > IOU_MID * (double)uni) m |= 1ull << jj;
                    }
                    if (vr == 0)
                        m &= (il < 63) ? (~0ull << (il + 1)) : 0ull;
                }
            }
            chunk[il * 33 + vr] = m;
        }
        __syncthreads();

        u64 cand = chunk[lane * 33];
        u64 cur = rem[w];
        int remn = nv - (w << 6);
        u64 vb = (remn >= 64) ? ~0ull : ((1ull << remn) - 1ull);
        u64 avail = vb & ~cur;
        u64 kept = 0;
        while (avail) {
            int bb = __ffsll(avail) - 1;
            kept |= 1ull << bb;
            cur |= __shfl(cand, bb, 64);
            avail &= ~(cur | (1ull << bb));
        }
        int vr = t & 31, pg = t >> 5;
        if (vr >= 1 && vr < nwr) {
            u64 acc = 0, km = kept;
            int n = 0;
            while (km) {
                int bb = __ffsll(km) - 1;
                km &= km - 1;
                if ((n & 31) == pg) acc |= chunk[bb * 33 + vr];
                ++n;
            }
            if (acc) atomicOr(&rem[w + vr], acc);
        }
        if (t == 0) rem[w] = cur;
        __syncthreads();
    }

    u16* inv = (u16*)chunk;
    for (int r = t; r < R; r += NTH) inv[r] = 0xffffu;
    __syncthreads();
    for (int i = t; i < nv; i += NTH)
        if (!((rem[i >> 6] >> (i & 63)) & 1ull))
            inv[(int)(vkey[i] & 0xffffffffu)] = (u16)i;
    __syncthreads();
    float* slice = out + (size_t)(c - 1) * R * 5;
    for (int r = t; r < R; r += NTH) {
        int i = inv[r];
        float v0 = 0.f, v1 = 0.f, v2 = 0.f, v3 = 0.f, v4 = 0.f;
        if (i != 0xffff) {
            float2 a1 = p1[i], a2 = p2[i];
            v0 = a1.x; v1 = a1.y; v2 = a2.x; v3 = a2.y;
            v4 = __uint_as_float(~(u32)(vkey[i] >> 32));
        }
        float* p = slice + (size_t)r * 5;
        p[0] = v0; p[1] = v1; p[2] = v2; p[3] = v3; p[4] = v4;
    }
}

extern "C" void kernel_launch(void* const* d_in, const int* in_sizes, int n_in,
                              void* d_out, int out_size, void* d_ws, size_t ws_size,
                              hipStream_t stream) {
    const float* loc    = (const float*)d_in[0];   // (R, 84) f32
    const float* scores = (const float*)d_in[1];   // (R, 21) f32
    const float* rois   = (const float*)d_in[2];   // (R, 4)  f32
    const int*   ph     = (const int*)d_in[3];
    const int*   pw     = (const int*)d_in[4];
    float* out = (float*)d_out;                    // (20, R, 5) f32
    int R = in_sizes[2] / 4;

    // ws: M | ord | pbG | arG | nvv
    size_t needM    = (size_t)NCO * RCAP * 32 * 8;       // 10.5 MB
    size_t needOrd  = (size_t)NCO * RCAP * 8;            // 328 KB
    size_t needPbG  = (size_t)NCO * RCAP * 16;           // 656 KB
    size_t needArG  = (size_t)NCO * RCAP * 4;            // 164 KB
    size_t need     = needM + needOrd + needPbG + needArG + 4096;

    if (R <= RCAP && ws_size >= need) {
        char* w     = (char*)d_ws;
        u64* M      = (u64*)w;                               w += needM;
        u64* ordp   = (u64*)w;                               w += needOrd;
        float4* pbG = (float4*)w;                            w += needPbG;
        float* arG  = (float*)w;                             w += needArG;
        int* nvv    = (int*)w;

        sortrank_kernel<<<NCO, 1024, 0, stream>>>(loc, scores, rois, ph, pw,
                                                  ordp, nvv, pbG, arG, R);
        maskp_kernel<<<NCO * SUB, 512, 0, stream>>>(pbG, arG, nvv, M);
        resolveout_kernel<<<NCO * SUB, TPB, 0, stream>>>(loc, rois, ph, pw,
                                                         ordp, nvv, M, out, R);
    } else if (R <= RMAX) {
        fused_kernel<<<NCO, NTH, 0, stream>>>(loc, scores, rois, ph, pw, out, R);
    }
}

// Round 10
// 117.965 us; speedup vs baseline: 1.1200x; 1.1200x over previous
//
#include <hip/hip_runtime.h>
#include <math.h>

#define NCLS 21
#define NCO 20
#define SUB 12                 // blocks per class (240 blocks <= 256 CUs; R25-proven)
#define TPB 256                // keygen/resolveout block size
#define RCAP 2048
#define RMAX 2000
#define SEGW 256               // ukey segment capacity (ceil(R/SUB)=167 <= 256)
#define LDSW 7680              // u64 capacity of resolve LDS stage (60 KB)
#define SCORE_THRESH 0.05f

typedef unsigned long long u64;
typedef unsigned int u32;
typedef unsigned short u16;

// Exact equivalent of (f32_div(inter,uni) > 0.3f):  inter > IOU_MID * uni in f64.
// 0.3f = 10066330*2^-25; midpoint to next float = 20132661*2^-26. RN tie at the
// midpoint rounds to even (0.3f) -> false, matching strict ">". 25b x 24b exact in f64.
#define IOU_MID (20132661.0 / 67108864.0)

__device__ __forceinline__ u64 readlane64(u64 v, int l) {
    u32 lo = (u32)__builtin_amdgcn_readlane((int)(u32)v, l);
    u32 hi = (u32)__builtin_amdgcn_readlane((int)(u32)(v >> 32), l);
    return ((u64)hi << 32) | lo;
}
__device__ __forceinline__ float readlanef(float v, int l) {
    return __uint_as_float((u32)__builtin_amdgcn_readlane((int)__float_as_uint(v), l));
}
__device__ __forceinline__ u64 shflxor64(u64 v, int m) {
    u32 lo = (u32)__shfl_xor((int)(u32)v, m, 64);
    u32 hi = (u32)__shfl_xor((int)(u32)(v >> 32), m, 64);
    return ((u64)hi << 32) | lo;
}

// Compact upper-triangle mask layout, per class:
// chunk ic (64 rows) starts at coff(ic); row (ic<<6)+il has W=nw-ic words
// (words v=ic..nw-1) at coff(ic) + il*W + (v-ic). Total = coff(nw) words.
__device__ __forceinline__ int coff(int ic, int nw) {
    return ((ic * nw - ((ic * (ic - 1)) >> 1)) << 6);
}

// Reference-exact box decode (absmax 0.0 through R1-R26).
__device__ __forceinline__ void decode_box(
    const float* __restrict__ rois, const float* __restrict__ loc,
    int r, int cls, float sh, float sw,
    float& by1, float& bx1, float& by2, float& bx2)
{
    float4 rb = *(const float4*)(rois + r * 4);
    float y1 = rb.x, x1 = rb.y, y2 = rb.z, x2 = rb.w;
    float h = y2 - y1, w = x2 - x1;
    float cy = y1 + 0.5f * h, cx = x1 + 0.5f * w;
    float4 l4 = *(const float4*)(loc + r * (NCLS * 4) + cls * 4);
    float dy = l4.x * 0.1f, dx = l4.y * 0.1f;
    float dh = l4.z * 0.2f, dw = l4.w * 0.2f;
    float ncy = dy * h + cy, ncx = dx * w + cx;
    float nh = expf(dh) * h, nw = expf(dw) * w;
    by1 = fminf(fmaxf(ncy - 0.5f * nh, 0.f), sh);
    bx1 = fminf(fmaxf(ncx - 0.5f * nw, 0.f), sw);
    by2 = fminf(fmaxf(ncy + 0.5f * nh, 0.f), sh);
    bx2 = fminf(fmaxf(ncx + 0.5f * nw, 0.f), sw);
}

// Reference-exact softmax prob (vectorized loads; float op ORDER k=0..20 kept
// identical to prior rounds: max then exp-sum in index order).
__device__ __forceinline__ float softmax_p(
    const float* __restrict__ scores, int r, int cls)
{
    const float* srow = scores + r * NCLS;
    float s[NCLS];
    float4 a0 = *(const float4*)(srow);
    float4 a1 = *(const float4*)(srow + 4);
    float4 a2 = *(const float4*)(srow + 8);
    float4 a3 = *(const float4*)(srow + 12);
    float4 a4 = *(const float4*)(srow + 16);
    s[0]=a0.x; s[1]=a0.y; s[2]=a0.z; s[3]=a0.w;
    s[4]=a1.x; s[5]=a1.y; s[6]=a1.z; s[7]=a1.w;
    s[8]=a2.x; s[9]=a2.y; s[10]=a2.z; s[11]=a2.w;
    s[12]=a3.x; s[13]=a3.y; s[14]=a3.z; s[15]=a3.w;
    s[16]=a4.x; s[17]=a4.y; s[18]=a4.z; s[19]=a4.w;
    s[20]=srow[20];
    float m = -INFINITY;
#pragma unroll
    for (int k = 0; k < NCLS; ++k) m = fmaxf(m, s[k]);
    float sum = 0.f, ec = 0.f;
#pragma unroll
    for (int k = 0; k < NCLS; ++k) {
        float e = expf(s[k] - m);
        sum += e;
        if (k == cls) ec = e;
    }
    return ec / sum;
}

// ---------------------------------------------------------------------------
// R27: REVERT to R25's proven 4-dispatch chain (111.75us best). R9-round
// post-mortem: the 4-way-split rank is LDS-PIPE-BOUND PER CU (~8000
// ds_read_b128/CU when a class concentrates in one block) -> every fusion
// alternative regressed (R7 +18, R9 +20, R22 +63, R23 +64); work must stay
// partitioned across >=200 CUs. This round's deltas are in-phase only:
// (1) maskp 512->1024 threads: 192 waves/class >= ntasks(~136) -> <=1
// upper-tri task per wave (was ~1.4) + staging latency hidden by 2x waves;
// (2) arG dropped - maskp recomputes ar=(z-x)*(w-y) from the staged pb
// (bit-identical: same inputs, same op).
// ---------------------------------------------------------------------------
__global__ __launch_bounds__(TPB) void keygen_kernel(
    const float* __restrict__ scores, u64* __restrict__ ukey,
    int* __restrict__ cntA, int R)
{
    __shared__ u64 lkey[TPB];
    __shared__ int cnt;
    const int t = threadIdx.x;
    const int c = blockIdx.x / SUB;
    const int s = blockIdx.x % SUB;
    const int lane = t & 63;
    if (t == 0) cnt = 0;
    __syncthreads();
    const int rpb = (R + SUB - 1) / SUB;     // 167 <= SEGW
    const int r0 = s * rpb, r1 = min(R, r0 + rpb);
    // Within a wave, loop-active lanes form a lane-prefix (r grows with
    // lane), so lane 0 is always active when any lane is.
    for (int r = r0 + t; r < r1; r += TPB) {
        float p = softmax_p(scores, r, c + 1);
        bool valid = (p > SCORE_THRESH);
        u64 key = ((u64)(~__float_as_uint(p)) << 32) | (u32)r;
        u64 bal = __ballot(valid);
        if (bal) {
            int nb = (int)__popcll(bal);
            int base = 0;
            if (lane == 0) base = atomicAdd(&cnt, nb);
            base = __shfl(base, 0, 64);
            if (valid)
                lkey[base + (int)__popcll(bal & ((1ull << lane) - 1ull))] = key;
        }
    }
    __syncthreads();
    const int n = cnt;
    if (t == 0) cntA[(c << 4) | s] = n;
    for (int j = t; j < n; j += TPB)
        ukey[(size_t)c * (SUB * SEGW) + s * SEGW + j] = lkey[j];
}

// ---------------------------------------------------------------------------
// rank: 240 blocks x 512 (R25-proven). Load the class's 12 key segments into
// compact LDS (wave wv copies segments wv and wv+8), rank a 1/12 contiguous
// slice via the 4-way j-split (4-lane group = one key; integer partial ranks
// shfl-combined - bit-exact), decode once into global pbG[rank]; s==0
// publishes ord/nvv.
// ---------------------------------------------------------------------------
__global__ __launch_bounds__(512) void rank_kernel(
    const float* __restrict__ loc, const float* __restrict__ rois,
    const int* __restrict__ ph, const int* __restrict__ pw,
    const u64* __restrict__ ukey, const int* __restrict__ cntA,
    u64* __restrict__ ord, int* __restrict__ nvv,
    float4* __restrict__ pbG, int R)
{
    __shared__ __align__(16) u64 vkey[RCAP + 2];
    const int t = threadIdx.x;
    const int c = blockIdx.x / SUB;
    const int s = blockIdx.x % SUB;
    const int wv = t >> 6, lane = t & 63;
    int nv = 0;
    int baseA = 0, nA = 0, baseB = 0, nB = 0;    // segments wv and wv+8
#pragma unroll
    for (int k = 0; k < SUB; ++k) {      // same-address broadcast loads
        int ck = cntA[(c << 4) | k];
        if (k < wv)     baseA += ck;
        if (k == wv)    nA = ck;
        if (k < wv + 8) baseB += ck;
        if (k == wv + 8) nB = ck;
        nv += ck;
    }
    for (int j = lane; j < nA; j += 64)
        vkey[baseA + j] = ukey[(size_t)c * (SUB * SEGW) + wv * SEGW + j];
    if (wv + 8 < SUB)
        for (int j = lane; j < nB; j += 64)
            vkey[baseB + j] = ukey[(size_t)c * (SUB * SEGW) + (wv + 8) * SEGW + j];
    if (t == 0) vkey[nv] = ~0ull;        // sentinel pad for b128 pairs
    __syncthreads();

    const int sl = (nv + SUB - 1) / SUB;       // this block's i-slice
    const int i0 = s * sl;
    const int nmy = max(0, min(nv - i0, sl));
    const int q = t & 3;                 // j-quarter; 4-lane group = one i
    const ulonglong2* vk2 = (const ulonglong2*)vkey;
    const int nj2 = (nv + 1) >> 1;
    const int jb0 = (q * nj2) >> 2;
    const int jb1 = ((q + 1) * nj2) >> 2;
    const float shf = (float)(*ph), swf = (float)(*pw);
    for (int il = (t >> 2); il < nmy; il += 128) {
        u64 kk = vkey[i0 + il];
        int rank = 0;
#pragma unroll 8
        for (int j = jb0; j < jb1; ++j) {
            ulonglong2 kj = vk2[j];      // same-address broadcast, 16B
            rank += (int)(kj.x < kk) + (int)(kj.y < kk);
        }
        rank += __shfl_xor(rank, 1, 64);     // combine 4-lane group
        rank += __shfl_xor(rank, 2, 64);     // (integer, exact)
        if (q == 0) {
            int r = (int)(u32)kk;
            float b0, b1, b2, b3;
            decode_box(rois, loc, r, c + 1, shf, swf, b0, b1, b2, b3);
            ord[((size_t)c << 11) + rank] = kk;
            pbG[((size_t)c << 11) + rank] = make_float4(b0, b1, b2, b3);
        }
    }
    if (t == 0 && s == 0) nvv[c] = nv;
}

// ---------------------------------------------------------------------------
// maskp: 240 blocks x 1024 (R27: 16 waves/block -> 192 waves/class >= ~136
// tasks, so <=1 task/wave). Stages pre-decoded sorted boxes into LDS and
// recomputes areas (bit-identical); mask math byte-identical to the proven
// structure.
// ---------------------------------------------------------------------------
__global__ __launch_bounds__(1024) void maskp_kernel(
    const float4* __restrict__ pbG, const int* __restrict__ nvv,
    u64* __restrict__ M)
{
    __shared__ float4 pb[RCAP];        // 32 KB sorted boxes
    __shared__ float ar[RCAP];         // 8 KB areas
    const int t = threadIdx.x;
    const int c = blockIdx.x / SUB;
    const int s = blockIdx.x % SUB;
    const int lane = t & 63;
    const int nv = nvv[c];
    const int nw = (nv + 63) >> 6;
    for (int i = t; i < nv; i += 1024) {
        float4 b = pbG[((size_t)c << 11) + i];
        pb[i] = b;
        ar[i] = (b.z - b.x) * (b.w - b.y);   // == rank's (b2-b0)*(b3-b1)
    }
    __syncthreads();

    const int wid = (s << 4) | (t >> 6);     // 0..SUB*16-1 waves per class
    const int ntasks = nw * (nw + 1) / 2;
    u64* Mc = M + ((size_t)c << 16);
    for (int task = wid; task < ntasks; task += SUB * 16) {
        int ic = 0, rm = task;
        while (rm >= nw - ic) { rm -= nw - ic; ++ic; }  // uniform, <=32 iters
        int v = ic + rm;
        int i = (ic << 6) + lane;
        float4 a = pb[i];                    // garbage if i>=nv (not stored)
        float iarea = ar[i];
        float4 rj = pb[(v << 6) + lane];     // loads executed by all lanes
        float ja_l = ar[(v << 6) + lane];
        int jcnt = min(64, nv - (v << 6));
        u64 m = 0;
        for (int jj = 0; jj < jcnt; ++jj) {
            float jy1 = readlanef(rj.x, jj);
            float jx1 = readlanef(rj.y, jj);
            float jy2 = readlanef(rj.z, jj);
            float jx2 = readlanef(rj.w, jj);
            float ja  = readlanef(ja_l, jj);
            float ty1 = fmaxf(a.x, jy1);
            float tx1 = fmaxf(a.y, jx1);
            float ty2 = fminf(a.z, jy2);
            float tx2 = fminf(a.w, jx2);
            float inter = fmaxf(ty2 - ty1, 0.f) * fmaxf(tx2 - tx1, 0.f);
            float uni = fmaxf(iarea + ja - inter, 1e-10f);
            if ((double)inter > IOU_MID * (double)uni) m |= 1ull << jj;
        }
        if (v == ic) m &= (lane < 63) ? (~0ull << (lane + 1)) : 0ull;
        int W = nw - ic;
        if (i < nv) Mc[coff(ic, nw) + lane * W + (v - ic)] = m;
    }
}

// ---------------------------------------------------------------------------
// resolveout: 240 blocks x 256 (proven core, R25 verbatim). Each sub-block
// stages/reads the class's compact mask, runs the resolve, then zeroes +
// scatters its 1/12 output slice.
// ---------------------------------------------------------------------------
__global__ __launch_bounds__(TPB) void resolveout_kernel(
    const float* __restrict__ loc, const float* __restrict__ rois,
    const int* __restrict__ ph, const int* __restrict__ pw,
    const u64* __restrict__ ord, const int* __restrict__ nvv,
    const u64* __restrict__ M, float* __restrict__ out, int R)
{
    __shared__ u64 mlds[LDSW];         // 60 KB compact mask
    __shared__ u64 keptw[32];
    const int t = threadIdx.x;
    const int c = blockIdx.x / SUB;
    const int s = blockIdx.x % SUB;
    const int nv = nvv[c];
    const int nw = (nv + 63) >> 6;
    const u64* Mc = M + ((size_t)c << 16);
    const int S = coff(nw, nw);
    const bool lds_ok = (S <= LDSW);
    if (t < 32) keptw[t] = 0;

    if (lds_ok) {
        for (int base = 0; base < S; base += 2048) {
            u64 v[8];
#pragma unroll
            for (int j = 0; j < 8; ++j) {      // 8 independent coalesced loads
                int k = base + (j << 8) + t;
                v[j] = (k < S) ? Mc[k] : 0ull;
            }
#pragma unroll
            for (int j = 0; j < 8; ++j) {
                int k = base + (j << 8) + t;
                if (k < S) mlds[k] = v[j];
            }
        }
    }
    __syncthreads();

    if (t < 64) {
        const int lane = t;
        auto core = [&](const auto* B) {
            u64 remreg = 0;                 // lane l owns removed-word l
            for (int w = 0; w < nw; ++w) {
                const int W = nw - w;
                const int cb = coff(w, nw);
                int i = (w << 6) + lane;
                u64 cw = (i < nv) ? B[cb + lane * W] : 0ull;   // diagonal word
                int remn = nv - (w << 6);
                u64 vb = (remn >= 64) ? ~0ull : ((1ull << remn) - 1ull);
                u64 cand = vb & ~readlane64(remreg, w);
                u64 X = cand;
                if (X) {
                    // in-word greedy fixpoint (ballot Jacobi; strict upper
                    // triangle => contrib bit l only from rows j<l =>
                    // fixpoint = greedy by index induction). R15-proven.
                    for (int it = 0; it < 64; ++it) {
                        u64 contrib = ((X >> lane) & 1ull) ? cw : 0ull;
#pragma unroll
                        for (int d = 1; d < 64; d <<= 1)
                            contrib |= shflxor64(contrib, d);
                        bool keep = ((cand >> lane) & 1ull) &&
                                    !((contrib >> lane) & 1ull);
                        u64 Xn = __ballot(keep);
                        if (Xn == X) break;
                        X = Xn;
                    }
                    if (lane == 0) keptw[w] = X;
                    // 8-wide batched propagation into later rem words
                    // (lane v owns word v); km=X is wave-uniform.
                    bool lact = (lane > w) && (lane < nw);
                    u64 km = X, acc = 0;
                    while (km) {
                        int bs[8];
#pragma unroll
                        for (int g = 0; g < 8; ++g) {
                            bs[g] = km ? (__ffsll(km) - 1) : -1;
                            if (km) km &= km - 1;
                        }
                        u64 tmp[8];
#pragma unroll
                        for (int g = 0; g < 8; ++g)
                            tmp[g] = (bs[g] >= 0 && lact)
                                ? B[cb + bs[g] * W + (lane - w)] : 0ull;
#pragma unroll
                        for (int g = 0; g < 8; ++g) acc |= tmp[g];
                    }
                    if (lact) remreg |= acc;
                }
            }
        };
        if (lds_ok) core(mlds); else core(Mc);
    }
    __syncthreads();

    // Output: zero this sub-block's slice, barrier (drains stores), scatter
    // kept rows whose roi index falls in range (decode recompute + prob bits).
    const int chunk = (R + SUB - 1) / SUB;
    const int r0 = s * chunk;
    const int r1 = min(R, r0 + chunk);
    float* slice = out + (size_t)c * R * 5;
    for (int k = r0 * 5 + t; k < r1 * 5; k += TPB) slice[k] = 0.f;
    __syncthreads();                    // drains the zero stores (vmcnt(0))

    const float sh = (float)(*ph), sw = (float)(*pw);
    for (int i = t; i < nv; i += TPB) {
        if ((keptw[i >> 6] >> (i & 63)) & 1ull) {
            u64 key = ord[((size_t)c << 11) + i];
            int r = (int)(u32)key;
            if (r >= r0 && r < r1) {
                float v0, v1, v2, v3;
                decode_box(rois, loc, r, c + 1, sh, sw, v0, v1, v2, v3);
                float* p = slice + (size_t)r * 5;
                p[0] = v0; p[1] = v1; p[2] = v2; p[3] = v3;
                p[4] = __uint_as_float(~(u32)(key >> 32));
            }
        }
    }
}

// --------------------------- fallback: R4 fused ----------------------------
#define NTH 1024
__global__ __launch_bounds__(NTH) void fused_kernel(
    const float* __restrict__ loc, const float* __restrict__ scores,
    const float* __restrict__ rois, const int* __restrict__ ph,
    const int* __restrict__ pw, float* __restrict__ out, int R)
{
    __shared__ u64 vkey[RMAX];
    __shared__ float2 p1[RMAX], p2[RMAX];
    __shared__ u64 chunk[64 * 33];
    __shared__ u64 rem[32];
    __shared__ int cnt;

    const int t = threadIdx.x;
    const int lane = t & 63;
    const int c = blockIdx.x + 1;
    const float sh = (float)(*ph), sw = (float)(*pw);

    if (t == 0) cnt = 0;
    if (t < 32) rem[t] = 0;
    __syncthreads();

    for (int r = t; r < R; r += NTH) {
        float p = softmax_p(scores, r, c);
        if (p > SCORE_THRESH) {
            int j = atomicAdd(&cnt, 1);
            vkey[j] = ((u64)(~__float_as_uint(p)) << 32) | (u32)r;
        }
    }
    __syncthreads();
    const int nv = cnt;
    const int nw = (nv + 63) >> 6;

    u64 kk0 = 0, kk1 = 0;
    int r0 = 0, r1 = 0;
    bool in0 = (t < nv), in1 = (t + NTH < nv);
    if (in0) kk0 = vkey[t];
    if (in1) kk1 = vkey[t + NTH];
#pragma unroll 8
    for (int i = 0; i < nv; ++i) {
        u64 k = vkey[i];
        r0 += (k < kk0);
        r1 += (k < kk1);
    }
    __syncthreads();

    for (int u = 0; u < 2; ++u) {
        bool act = u ? in1 : in0;
        if (act) {
            u64 kk = u ? kk1 : kk0;
            int rank = u ? r1 : r0;
            int r = (int)(kk & 0xffffffffu);
            float b0, b1, b2, b3;
            decode_box(rois, loc, r, c, sh, sw, b0, b1, b2, b3);
            vkey[rank] = kk;
            p1[rank] = make_float2(b0, b1);
            p2[rank] = make_float2(b2, b3);
        }
    }
    __syncthreads();

    for (int w = 0; w < nw; ++w) {
        int nwr = nw - w;
        u64 remw = rem[w];
        for (int task = t; task < (nwr << 6); task += NTH) {
            int vr = task >> 6, il = task & 63;
            int i = (w << 6) + il;
            u64 m = 0;
            if (i < nv && !((remw >> il) & 1ull)) {
                int v = w + vr;
                u64 rv = rem[v];
                if (~rv != 0ull) {
                    float2 a1 = p1[i], a2 = p2[i];
                    float iarea = (a2.x - a1.x) * (a2.y - a1.y);
                    int j0 = v << 6;
                    int jhi = min(64, nv - j0);
#pragma unroll 4
                    for (int jj = 0; jj < jhi; ++jj) {
                        float2 b1 = p1[j0 + jj], b2 = p2[j0 + jj];
                        float ty1 = fmaxf(a1.x, b1.x);
                        float tx1 = fmaxf(a1.y, b1.y);
                        float ty2 = fminf(a2.x, b2.x);
                        float tx2 = fminf(a2.y, b2.y);
                        float inter = fmaxf(ty2 - ty1, 0.f) * fmaxf(tx2 - tx1, 0.f);
                        float jarea = (b2.x - b1.x) * (b2.y - b1.y);
                        float uni = fmaxf(iarea + jarea - inter, 1e-10f);
                        if ((double)inter > IOU_MID * (double)uni) m |= 1ull << jj;
                    }
                    if (vr == 0)
                        m &= (il < 63) ? (~0ull << (il + 1)) : 0ull;
                }
            }
            chunk[il * 33 + vr] = m;
        }
        __syncthreads();

        u64 cand = chunk[lane * 33];
        u64 cur = rem[w];
        int remn = nv - (w << 6);
        u64 vb = (remn >= 64) ? ~0ull : ((1ull << remn) - 1ull);
        u64 avail = vb & ~cur;
        u64 kept = 0;
        while (avail) {
            int bb = __ffsll(avail) - 1;
            kept |= 1ull << bb;
            cur |= __shfl(cand, bb, 64);
            avail &= ~(cur | (1ull << bb));
        }
        int vr = t & 31, pg = t >> 5;
        if (vr >= 1 && vr < nwr) {
            u64 acc = 0, km = kept;
            int n = 0;
            while (km) {
                int bb = __ffsll(km) - 1;
                km &= km - 1;
                if ((n & 31) == pg) acc |= chunk[bb * 33 + vr];
                ++n;
            }
            if (acc) atomicOr(&rem[w + vr], acc);
        }
        if (t == 0) rem[w] = cur;
        __syncthreads();
    }

    u16* inv = (u16*)chunk;
    for (int r = t; r < R; r += NTH) inv[r] = 0xffffu;
    __syncthreads();
    for (int i = t; i < nv; i += NTH)
        if (!((rem[i >> 6] >> (i & 63)) & 1ull))
            inv[(int)(vkey[i] & 0xffffffffu)] = (u16)i;
    __syncthreads();
    float* slice = out + (size_t)(c - 1) * R * 5;
    for (int r = t; r < R; r += NTH) {
        int i = inv[r];
        float v0 = 0.f, v1 = 0.f, v2 = 0.f, v3 = 0.f, v4 = 0.f;
        if (i != 0xffff) {
            float2 a1 = p1[i], a2 = p2[i];
            v0 = a1.x; v1 = a1.y; v2 = a2.x; v3 = a2.y;
            v4 = __uint_as_float(~(u32)(vkey[i] >> 32));
        }
        float* p = slice + (size_t)r * 5;
        p[0] = v0; p[1] = v1; p[2] = v2; p[3] = v3; p[4] = v4;
    }
}

extern "C" void kernel_launch(void* const* d_in, const int* in_sizes, int n_in,
                              void* d_out, int out_size, void* d_ws, size_t ws_size,
                              hipStream_t stream) {
    const float* loc    = (const float*)d_in[0];   // (R, 84) f32
    const float* scores = (const float*)d_in[1];   // (R, 21) f32
    const float* rois   = (const float*)d_in[2];   // (R, 4)  f32
    const int*   ph     = (const int*)d_in[3];
    const int*   pw     = (const int*)d_in[4];
    float* out = (float*)d_out;                    // (20, R, 5) f32
    int R = in_sizes[2] / 4;

    // ws: M | ord | ukey[NCO][SUB*SEGW] | pbG | cntA[NCO*16] | nvv
    size_t needM    = (size_t)NCO * RCAP * 32 * 8;       // 10.5 MB
    size_t needOrd  = (size_t)NCO * RCAP * 8;            // 328 KB
    size_t needUkey = (size_t)NCO * SUB * SEGW * 8;      // 480 KB
    size_t needPbG  = (size_t)NCO * RCAP * 16;           // 656 KB
    size_t need     = needM + needOrd + needUkey + needPbG + 4096;

    if (R <= RCAP && R <= SUB * SEGW && ws_size >= need) {
        char* w     = (char*)d_ws;
        u64* M      = (u64*)w;                               w += needM;
        u64* ordp   = (u64*)w;                               w += needOrd;
        u64* ukey   = (u64*)w;                               w += needUkey;
        float4* pbG = (float4*)w;                            w += needPbG;
        int* cntA   = (int*)w;                               w += 2048;
        int* nvv    = (int*)w;

        keygen_kernel<<<NCO * SUB, TPB, 0, stream>>>(scores, ukey, cntA, R);
        rank_kernel<<<NCO * SUB, 512, 0, stream>>>(loc, rois, ph, pw, ukey,
                                                   cntA, ordp, nvv, pbG, R);
        maskp_kernel<<<NCO * SUB, 1024, 0, stream>>>(pbG, nvv, M);
        resolveout_kernel<<<NCO * SUB, TPB, 0, stream>>>(loc, rois, ph, pw,
                                                         ordp, nvv, M, out, R);
    } else if (R <= RMAX) {
        fused_kernel<<<NCO, NTH, 0, stream>>>(loc, scores, rois, ph, pw, out, R);
    }
}

// Round 11
// 110.835 us; speedup vs baseline: 1.1921x; 1.0643x over previous
//
#include <hip/hip_runtime.h>
#include <math.h>

#define NCLS 21
#define NCO 20
#define SUB 12                 // blocks per class (R25-proven: 240 blocks ~ 94% of CUs)
#define TPB 256                // keygen/resolveout block size
#define RCAP 2048
#define RMAX 2000
#define SEGW 256               // ukey segment capacity (ceil(R/SUB)=167 <= 256)
#define LDSW 7680              // u64 capacity of resolve LDS stage (60 KB)
#define SCORE_THRESH 0.05f

typedef unsigned long long u64;
typedef unsigned int u32;
typedef unsigned short u16;

// Exact equivalent of (f32_div(inter,uni) > 0.3f):  inter > IOU_MID * uni in f64.
// 0.3f = 10066330*2^-25; midpoint to next float = 20132661*2^-26. RN tie at the
// midpoint rounds to even (0.3f) -> false, matching strict ">". 25b x 24b exact in f64.
#define IOU_MID (20132661.0 / 67108864.0)

__device__ __forceinline__ u64 readlane64(u64 v, int l) {
    u32 lo = (u32)__builtin_amdgcn_readlane((int)(u32)v, l);
    u32 hi = (u32)__builtin_amdgcn_readlane((int)(u32)(v >> 32), l);
    return ((u64)hi << 32) | lo;
}
__device__ __forceinline__ float readlanef(float v, int l) {
    return __uint_as_float((u32)__builtin_amdgcn_readlane((int)__float_as_uint(v), l));
}
__device__ __forceinline__ u64 shflxor64(u64 v, int m) {
    u32 lo = (u32)__shfl_xor((int)(u32)v, m, 64);
    u32 hi = (u32)__shfl_xor((int)(u32)(v >> 32), m, 64);
    return ((u64)hi << 32) | lo;
}

// Compact upper-triangle mask layout, per class:
// chunk ic (64 rows) starts at coff(ic); row (ic<<6)+il has W=nw-ic words
// (words v=ic..nw-1) at coff(ic) + il*W + (v-ic). Total = coff(nw) words.
__device__ __forceinline__ int coff(int ic, int nw) {
    return ((ic * nw - ((ic * (ic - 1)) >> 1)) << 6);
}

// Reference-exact box decode (absmax 0.0 through R1-R27).
__device__ __forceinline__ void decode_box(
    const float* __restrict__ rois, const float* __restrict__ loc,
    int r, int cls, float sh, float sw,
    float& by1, float& bx1, float& by2, float& bx2)
{
    float4 rb = *(const float4*)(rois + r * 4);
    float y1 = rb.x, x1 = rb.y, y2 = rb.z, x2 = rb.w;
    float h = y2 - y1, w = x2 - x1;
    float cy = y1 + 0.5f * h, cx = x1 + 0.5f * w;
    float4 l4 = *(const float4*)(loc + r * (NCLS * 4) + cls * 4);
    float dy = l4.x * 0.1f, dx = l4.y * 0.1f;
    float dh = l4.z * 0.2f, dw = l4.w * 0.2f;
    float ncy = dy * h + cy, ncx = dx * w + cx;
    float nh = expf(dh) * h, nw = expf(dw) * w;
    by1 = fminf(fmaxf(ncy - 0.5f * nh, 0.f), sh);
    bx1 = fminf(fmaxf(ncx - 0.5f * nw, 0.f), sw);
    by2 = fminf(fmaxf(ncy + 0.5f * nh, 0.f), sh);
    bx2 = fminf(fmaxf(ncx + 0.5f * nw, 0.f), sw);
}

// Reference-exact softmax prob (vectorized loads; float op ORDER k=0..20 kept
// identical to prior rounds: max then exp-sum in index order).
__device__ __forceinline__ float softmax_p(
    const float* __restrict__ scores, int r, int cls)
{
    const float* srow = scores + r * NCLS;
    float s[NCLS];
    float4 a0 = *(const float4*)(srow);
    float4 a1 = *(const float4*)(srow + 4);
    float4 a2 = *(const float4*)(srow + 8);
    float4 a3 = *(const float4*)(srow + 12);
    float4 a4 = *(const float4*)(srow + 16);
    s[0]=a0.x; s[1]=a0.y; s[2]=a0.z; s[3]=a0.w;
    s[4]=a1.x; s[5]=a1.y; s[6]=a1.z; s[7]=a1.w;
    s[8]=a2.x; s[9]=a2.y; s[10]=a2.z; s[11]=a2.w;
    s[12]=a3.x; s[13]=a3.y; s[14]=a3.z; s[15]=a3.w;
    s[16]=a4.x; s[17]=a4.y; s[18]=a4.z; s[19]=a4.w;
    s[20]=srow[20];
    float m = -INFINITY;
#pragma unroll
    for (int k = 0; k < NCLS; ++k) m = fmaxf(m, s[k]);
    float sum = 0.f, ec = 0.f;
#pragma unroll
    for (int k = 0; k < NCLS; ++k) {
        float e = expf(s[k] - m);
        sum += e;
        if (k == cls) ec = e;
    }
    return ec / sum;
}

// ---------------------------------------------------------------------------
// R28: REVERT to R25 verbatim (measured 111.75us best). R27 post-mortem:
// maskp@1024 + arG-drop bundled change regressed +6.2us (block critical path
// = slowest of 16 waves + launch ramp; "fewer tasks/wave" theory wrong at
// this scale). Measured-and-rejected structural alternatives: in-kernel grid
// sync (+63), flag sync (+64), 3-dispatch redundant-rank (+18), 1-block-per-
// class fusion (+20), SUB=8 (+5), maskp@1024 (+6). Remaining time = ~81us
// harness poison fills (83% HBM peak, not kernel-addressable) + ~19us launch
// overhead + ~11us phase work.
// ---------------------------------------------------------------------------
__global__ __launch_bounds__(TPB) void keygen_kernel(
    const float* __restrict__ scores, u64* __restrict__ ukey,
    int* __restrict__ cntA, int R)
{
    __shared__ u64 lkey[TPB];
    __shared__ int cnt;
    const int t = threadIdx.x;
    const int c = blockIdx.x / SUB;
    const int s = blockIdx.x % SUB;
    const int lane = t & 63;
    if (t == 0) cnt = 0;
    __syncthreads();
    const int rpb = (R + SUB - 1) / SUB;     // 167 <= SEGW
    const int r0 = s * rpb, r1 = min(R, r0 + rpb);
    // Within a wave, loop-active lanes form a lane-prefix (r grows with
    // lane), so lane 0 is always active when any lane is.
    for (int r = r0 + t; r < r1; r += TPB) {
        float p = softmax_p(scores, r, c + 1);
        bool valid = (p > SCORE_THRESH);
        u64 key = ((u64)(~__float_as_uint(p)) << 32) | (u32)r;
        u64 bal = __ballot(valid);
        if (bal) {
            int nb = (int)__popcll(bal);
            int base = 0;
            if (lane == 0) base = atomicAdd(&cnt, nb);
            base = __shfl(base, 0, 64);
            if (valid)
                lkey[base + (int)__popcll(bal & ((1ull << lane) - 1ull))] = key;
        }
    }
    __syncthreads();
    const int n = cnt;
    if (t == 0) cntA[(c << 4) | s] = n;
    for (int j = t; j < n; j += TPB)
        ukey[(size_t)c * (SUB * SEGW) + s * SEGW + j] = lkey[j];
}

// ---------------------------------------------------------------------------
// rank: 240 blocks x 512. Load the class's 12 key segments into compact LDS
// (wave wv copies segments wv and wv+8), rank a 1/12 contiguous slice via the
// R22-proven 4-way j-split (4-lane group = one key; integer partial ranks
// shfl-combined - bit-exact), decode once into global pbG/arG[rank]; s==0
// publishes ord/nvv.
// ---------------------------------------------------------------------------
__global__ __launch_bounds__(512) void rank_kernel(
    const float* __restrict__ loc, const float* __restrict__ rois,
    const int* __restrict__ ph, const int* __restrict__ pw,
    const u64* __restrict__ ukey, const int* __restrict__ cntA,
    u64* __restrict__ ord, int* __restrict__ nvv,
    float4* __restrict__ pbG, float* __restrict__ arG, int R)
{
    __shared__ __align__(16) u64 vkey[RCAP + 2];
    const int t = threadIdx.x;
    const int c = blockIdx.x / SUB;
    const int s = blockIdx.x % SUB;
    const int wv = t >> 6, lane = t & 63;
    int nv = 0;
    int baseA = 0, nA = 0, baseB = 0, nB = 0;    // segments wv and wv+8
#pragma unroll
    for (int k = 0; k < SUB; ++k) {      // same-address broadcast loads
        int ck = cntA[(c << 4) | k];
        if (k < wv)     baseA += ck;
        if (k == wv)    nA = ck;
        if (k < wv + 8) baseB += ck;
        if (k == wv + 8) nB = ck;
        nv += ck;
    }
    for (int j = lane; j < nA; j += 64)
        vkey[baseA + j] = ukey[(size_t)c * (SUB * SEGW) + wv * SEGW + j];
    if (wv + 8 < SUB)
        for (int j = lane; j < nB; j += 64)
            vkey[baseB + j] = ukey[(size_t)c * (SUB * SEGW) + (wv + 8) * SEGW + j];
    if (t == 0) vkey[nv] = ~0ull;        // sentinel pad for b128 pairs
    __syncthreads();

    const int sl = (nv + SUB - 1) / SUB;       // this block's i-slice
    const int i0 = s * sl;
    const int nmy = max(0, min(nv - i0, sl));
    const int q = t & 3;                 // j-quarter; 4-lane group = one i
    const ulonglong2* vk2 = (const ulonglong2*)vkey;
    const int nj2 = (nv + 1) >> 1;
    const int jb0 = (q * nj2) >> 2;
    const int jb1 = ((q + 1) * nj2) >> 2;
    const float shf = (float)(*ph), swf = (float)(*pw);
    for (int il = (t >> 2); il < nmy; il += 128) {
        u64 kk = vkey[i0 + il];
        int rank = 0;
#pragma unroll 8
        for (int j = jb0; j < jb1; ++j) {
            ulonglong2 kj = vk2[j];      // same-address broadcast, 16B
            rank += (int)(kj.x < kk) + (int)(kj.y < kk);
        }
        rank += __shfl_xor(rank, 1, 64);     // combine 4-lane group
        rank += __shfl_xor(rank, 2, 64);     // (integer, exact)
        if (q == 0) {
            int r = (int)(u32)kk;
            float b0, b1, b2, b3;
            decode_box(rois, loc, r, c + 1, shf, swf, b0, b1, b2, b3);
            ord[((size_t)c << 11) + rank] = kk;
            pbG[((size_t)c << 11) + rank] = make_float4(b0, b1, b2, b3);
            arG[((size_t)c << 11) + rank] = (b2 - b0) * (b3 - b1);
        }
    }
    if (t == 0 && s == 0) nvv[c] = nv;
}

// ---------------------------------------------------------------------------
// maskp: 240 blocks x 512. Loads pre-decoded sorted boxes (coalesced float4,
// no exp) into LDS; mask phase byte-identical to the proven structure, now
// 96 waves/class (~1.4 upper-tri tasks each).
// ---------------------------------------------------------------------------
__global__ __launch_bounds__(512) void maskp_kernel(
    const float4* __restrict__ pbG, const float* __restrict__ arG,
    const int* __restrict__ nvv, u64* __restrict__ M)
{
    __shared__ float4 pb[RCAP];        // 32 KB sorted boxes
    __shared__ float ar[RCAP];         // 8 KB areas
    const int t = threadIdx.x;
    const int c = blockIdx.x / SUB;
    const int s = blockIdx.x % SUB;
    const int lane = t & 63;
    const int nv = nvv[c];
    const int nw = (nv + 63) >> 6;
    for (int i = t; i < nv; i += 512) {
        pb[i] = pbG[((size_t)c << 11) + i];
        ar[i] = arG[((size_t)c << 11) + i];
    }
    __syncthreads();

    const int wid = (s << 3) | (t >> 6);     // 0..SUB*8-1 waves per class
    const int ntasks = nw * (nw + 1) / 2;
    u64* Mc = M + ((size_t)c << 16);
    for (int task = wid; task < ntasks; task += SUB * 8) {
        int ic = 0, rm = task;
        while (rm >= nw - ic) { rm -= nw - ic; ++ic; }  // uniform, <=32 iters
        int v = ic + rm;
        int i = (ic << 6) + lane;
        float4 a = pb[i];                    // garbage if i>=nv (not stored)
        float iarea = ar[i];
        float4 rj = pb[(v << 6) + lane];     // loads executed by all lanes
        float ja_l = ar[(v << 6) + lane];
        int jcnt = min(64, nv - (v << 6));
        u64 m = 0;
        for (int jj = 0; jj < jcnt; ++jj) {
            float jy1 = readlanef(rj.x, jj);
            float jx1 = readlanef(rj.y, jj);
            float jy2 = readlanef(rj.z, jj);
            float jx2 = readlanef(rj.w, jj);
            float ja  = readlanef(ja_l, jj);
            float ty1 = fmaxf(a.x, jy1);
            float tx1 = fmaxf(a.y, jx1);
            float ty2 = fminf(a.z, jy2);
            float tx2 = fminf(a.w, jx2);
            float inter = fmaxf(ty2 - ty1, 0.f) * fmaxf(tx2 - tx1, 0.f);
            float uni = fmaxf(iarea + ja - inter, 1e-10f);
            if ((double)inter > IOU_MID * (double)uni) m |= 1ull << jj;
        }
        if (v == ic) m &= (lane < 63) ? (~0ull << (lane + 1)) : 0ull;
        int W = nw - ic;
        if (i < nv) Mc[coff(ic, nw) + lane * W + (v - ic)] = m;
    }
}

// ---------------------------------------------------------------------------
// resolveout: 240 blocks x 256 (proven core). Each sub-block stages/reads the
// class's compact mask, runs the resolve, then zeroes + scatters its 1/12
// output slice.
// ---------------------------------------------------------------------------
__global__ __launch_bounds__(TPB) void resolveout_kernel(
    const float* __restrict__ loc, const float* __restrict__ rois,
    const int* __restrict__ ph, const int* __restrict__ pw,
    const u64* __restrict__ ord, const int* __restrict__ nvv,
    const u64* __restrict__ M, float* __restrict__ out, int R)
{
    __shared__ u64 mlds[LDSW];         // 60 KB compact mask
    __shared__ u64 keptw[32];
    const int t = threadIdx.x;
    const int c = blockIdx.x / SUB;
    const int s = blockIdx.x % SUB;
    const int nv = nvv[c];
    const int nw = (nv + 63) >> 6;
    const u64* Mc = M + ((size_t)c << 16);
    const int S = coff(nw, nw);
    const bool lds_ok = (S <= LDSW);
    if (t < 32) keptw[t] = 0;

    if (lds_ok) {
        for (int base = 0; base < S; base += 2048) {
            u64 v[8];
#pragma unroll
            for (int j = 0; j < 8; ++j) {      // 8 independent coalesced loads
                int k = base + (j << 8) + t;
                v[j] = (k < S) ? Mc[k] : 0ull;
            }
#pragma unroll
            for (int j = 0; j < 8; ++j) {
                int k = base + (j << 8) + t;
                if (k < S) mlds[k] = v[j];
            }
        }
    }
    __syncthreads();

    if (t < 64) {
        const int lane = t;
        auto core = [&](const auto* B) {
            u64 remreg = 0;                 // lane l owns removed-word l
            for (int w = 0; w < nw; ++w) {
                const int W = nw - w;
                const int cb = coff(w, nw);
                int i = (w << 6) + lane;
                u64 cw = (i < nv) ? B[cb + lane * W] : 0ull;   // diagonal word
                int remn = nv - (w << 6);
                u64 vb = (remn >= 64) ? ~0ull : ((1ull << remn) - 1ull);
                u64 cand = vb & ~readlane64(remreg, w);
                u64 X = cand;
                if (X) {
                    // in-word greedy fixpoint (ballot Jacobi; strict upper
                    // triangle => contrib bit l only from rows j<l =>
                    // fixpoint = greedy by index induction). R15-proven.
                    for (int it = 0; it < 64; ++it) {
                        u64 contrib = ((X >> lane) & 1ull) ? cw : 0ull;
#pragma unroll
                        for (int d = 1; d < 64; d <<= 1)
                            contrib |= shflxor64(contrib, d);
                        bool keep = ((cand >> lane) & 1ull) &&
                                    !((contrib >> lane) & 1ull);
                        u64 Xn = __ballot(keep);
                        if (Xn == X) break;
                        X = Xn;
                    }
                    if (lane == 0) keptw[w] = X;
                    // 8-wide batched propagation into later rem words
                    // (lane v owns word v); km=X is wave-uniform.
                    bool lact = (lane > w) && (lane < nw);
                    u64 km = X, acc = 0;
                    while (km) {
                        int bs[8];
#pragma unroll
                        for (int g = 0; g < 8; ++g) {
                            bs[g] = km ? (__ffsll(km) - 1) : -1;
                            if (km) km &= km - 1;
                        }
                        u64 tmp[8];
#pragma unroll
                        for (int g = 0; g < 8; ++g)
                            tmp[g] = (bs[g] >= 0 && lact)
                                ? B[cb + bs[g] * W + (lane - w)] : 0ull;
#pragma unroll
                        for (int g = 0; g < 8; ++g) acc |= tmp[g];
                    }
                    if (lact) remreg |= acc;
                }
            }
        };
        if (lds_ok) core(mlds); else core(Mc);
    }
    __syncthreads();

    // Output: zero this sub-block's slice, barrier (drains stores), scatter
    // kept rows whose roi index falls in range (decode recompute + prob bits).
    const int chunk = (R + SUB - 1) / SUB;
    const int r0 = s * chunk;
    const int r1 = min(R, r0 + chunk);
    float* slice = out + (size_t)c * R * 5;
    for (int k = r0 * 5 + t; k < r1 * 5; k += TPB) slice[k] = 0.f;
    __syncthreads();                    // drains the zero stores (vmcnt(0))

    const float sh = (float)(*ph), sw = (float)(*pw);
    for (int i = t; i < nv; i += TPB) {
        if ((keptw[i >> 6] >> (i & 63)) & 1ull) {
            u64 key = ord[((size_t)c << 11) + i];
            int r = (int)(u32)key;
            if (r >= r0 && r < r1) {
                float v0, v1, v2, v3;
                decode_box(rois, loc, r, c + 1, sh, sw, v0, v1, v2, v3);
                float* p = slice + (size_t)r * 5;
                p[0] = v0; p[1] = v1; p[2] = v2; p[3] = v3;
                p[4] = __uint_as_float(~(u32)(key >> 32));
            }
        }
    }
}

// --------------------------- fallback: R4 fused ----------------------------
#define NTH 1024
__global__ __launch_bounds__(NTH) void fused_kernel(
    const float* __restrict__ loc, const float* __restrict__ scores,
    const float* __restrict__ rois, const int* __restrict__ ph,
    const int* __restrict__ pw, float* __restrict__ out, int R)
{
    __shared__ u64 vkey[RMAX];
    __shared__ float2 p1[RMAX], p2[RMAX];
    __shared__ u64 chunk[64 * 33];
    __shared__ u64 rem[32];
    __shared__ int cnt;

    const int t = threadIdx.x;
    const int lane = t & 63;
    const int c = blockIdx.x + 1;
    const float sh = (float)(*ph), sw = (float)(*pw);

    if (t == 0) cnt = 0;
    if (t < 32) rem[t] = 0;
    __syncthreads();

    for (int r = t; r < R; r += NTH) {
        float p = softmax_p(scores, r, c);
        if (p > SCORE_THRESH) {
            int j = atomicAdd(&cnt, 1);
            vkey[j] = ((u64)(~__float_as_uint(p)) << 32) | (u32)r;
        }
    }
    __syncthreads();
    const int nv = cnt;
    const int nw = (nv + 63) >> 6;

    u64 kk0 = 0, kk1 = 0;
    int r0 = 0, r1 = 0;
    bool in0 = (t < nv), in1 = (t + NTH < nv);
    if (in0) kk0 = vkey[t];
    if (in1) kk1 = vkey[t + NTH];
#pragma unroll 8
    for (int i = 0; i < nv; ++i) {
        u64 k = vkey[i];
        r0 += (k < kk0);
        r1 += (k < kk1);
    }
    __syncthreads();

    for (int u = 0; u < 2; ++u) {
        bool act = u ? in1 : in0;
        if (act) {
            u64 kk = u ? kk1 : kk0;
            int rank = u ? r1 : r0;
            int r = (int)(kk & 0xffffffffu);
            float b0, b1, b2, b3;
            decode_box(rois, loc, r, c, sh, sw, b0, b1, b2, b3);
            vkey[rank] = kk;
            p1[rank] = make_float2(b0, b1);
            p2[rank] = make_float2(b2, b3);
        }
    }
    __syncthreads();

    for (int w = 0; w < nw; ++w) {
        int nwr = nw - w;
        u64 remw = rem[w];
        for (int task = t; task < (nwr << 6); task += NTH) {
            int vr = task >> 6, il = task & 63;
            int i = (w << 6) + il;
            u64 m = 0;
            if (i < nv && !((remw >> il) & 1ull)) {
                int v = w + vr;
                u64 rv = rem[v];
                if (~rv != 0ull) {
                    float2 a1 = p1[i], a2 = p2[i];
                    float iarea = (a2.x - a1.x) * (a2.y - a1.y);
                    int j0 = v << 6;
                    int jhi = min(64, nv - j0);
#pragma unroll 4
                    for (int jj = 0; jj < jhi; ++jj) {
                        float2 b1 = p1[j0 + jj], b2 = p2[j0 + jj];
                        float ty1 = fmaxf(a1.x, b1.x);
                        float tx1 = fmaxf(a1.y, b1.y);
                        float ty2 = fminf(a2.x, b2.x);
                        float tx2 = fminf(a2.y, b2.y);
                        float inter = fmaxf(ty2 - ty1, 0.f) * fmaxf(tx2 - tx1, 0.f);
                        float jarea = (b2.x - b1.x) * (b2.y - b1.y);
                        float uni = fmaxf(iarea + jarea - inter, 1e-10f);
                        if ((double)inter > IOU_MID * (double)uni) m |= 1ull << jj;
                    }
                    if (vr == 0)
                        m &= (il < 63) ? (~0ull << (il + 1)) : 0ull;
                }
            }
            chunk[il * 33 + vr] = m;
        }
        __syncthreads();

        u64 cand = chunk[lane * 33];
        u64 cur = rem[w];
        int remn = nv - (w << 6);
        u64 vb = (remn >= 64) ? ~0ull : ((1ull << remn) - 1ull);
        u64 avail = vb & ~cur;
        u64 kept = 0;
        while (avail) {
            int bb = __ffsll(avail) - 1;
            kept |= 1ull << bb;
            cur |= __shfl(cand, bb, 64);
            avail &= ~(cur | (1ull << bb));
        }
        int vr = t & 31, pg = t >> 5;
        if (vr >= 1 && vr < nwr) {
            u64 acc = 0, km = kept;
            int n = 0;
            while (km) {
                int bb = __ffsll(km) - 1;
                km &= km - 1;
                if ((n & 31) == pg) acc |= chunk[bb * 33 + vr];
                ++n;
            }
            if (acc) atomicOr(&rem[w + vr], acc);
        }
        if (t == 0) rem[w] = cur;
        __syncthreads();
    }

    u16* inv = (u16*)chunk;
    for (int r = t; r < R; r += NTH) inv[r] = 0xffffu;
    __syncthreads();
    for (int i = t; i < nv; i += NTH)
        if (!((rem[i >> 6] >> (i & 63)) & 1ull))
            inv[(int)(vkey[i] & 0xffffffffu)] = (u16)i;
    __syncthreads();
    float* slice = out + (size_t)(c - 1) * R * 5;
    for (int r = t; r < R; r += NTH) {
        int i = inv[r];
        float v0 = 0.f, v1 = 0.f, v2 = 0.f, v3 = 0.f, v4 = 0.f;
        if (i != 0xffff) {
            float2 a1 = p1[i], a2 = p2[i];
            v0 = a1.x; v1 = a1.y; v2 = a2.x; v3 = a2.y;
            v4 = __uint_as_float(~(u32)(vkey[i] >> 32));
        }
        float* p = slice + (size_t)r * 5;
        p[0] = v0; p[1] = v1; p[2] = v2; p[3] = v3; p[4] = v4;
    }
}

extern "C" void kernel_launch(void* const* d_in, const int* in_sizes, int n_in,
                              void* d_out, int out_size, void* d_ws, size_t ws_size,
                              hipStream_t stream) {
    const float* loc    = (const float*)d_in[0];   // (R, 84) f32
    const float* scores = (const float*)d_in[1];   // (R, 21) f32
    const float* rois   = (const float*)d_in[2];   // (R, 4)  f32
    const int*   ph     = (const int*)d_in[3];
    const int*   pw     = (const int*)d_in[4];
    float* out = (float*)d_out;                    // (20, R, 5) f32
    int R = in_sizes[2] / 4;

    // ws: M | ord | ukey[NCO][SUB*SEGW] | pbG | arG | cntA[NCO*16] | nvv
    size_t needM    = (size_t)NCO * RCAP * 32 * 8;       // 10.5 MB
    size_t needOrd  = (size_t)NCO * RCAP * 8;            // 328 KB
    size_t needUkey = (size_t)NCO * SUB * SEGW * 8;      // 480 KB
    size_t needPbG  = (size_t)NCO * RCAP * 16;           // 656 KB
    size_t needArG  = (size_t)NCO * RCAP * 4;            // 164 KB
    size_t need     = needM + needOrd + needUkey + needPbG + needArG + 4096;

    if (R <= RCAP && R <= SUB * SEGW && ws_size >= need) {
        char* w     = (char*)d_ws;
        u64* M      = (u64*)w;                               w += needM;
        u64* ordp   = (u64*)w;                               w += needOrd;
        u64* ukey   = (u64*)w;                               w += needUkey;
        float4* pbG = (float4*)w;                            w += needPbG;
        float* arG  = (float*)w;                             w += needArG;
        int* cntA   = (int*)w;                               w += 2048;
        int* nvv    = (int*)w;

        keygen_kernel<<<NCO * SUB, TPB, 0, stream>>>(scores, ukey, cntA, R);
        rank_kernel<<<NCO * SUB, 512, 0, stream>>>(loc, rois, ph, pw, ukey,
                                                   cntA, ordp, nvv, pbG, arG, R);
        maskp_kernel<<<NCO * SUB, 512, 0, stream>>>(pbG, arG, nvv, M);
        resolveout_kernel<<<NCO * SUB, TPB, 0, stream>>>(loc, rois, ph, pw,
                                                         ordp, nvv, M, out, R);
    } else if (R <= RMAX) {
        fused_kernel<<<NCO, NTH, 0, stream>>>(loc, scores, rois, ph, pw, out, R);
    }
}